// Round 2
// baseline (231.810 us; speedup 1.0000x reference)
//
#include <hip/hip_runtime.h>
#include <hip/hip_cooperative_groups.h>
#include <cmath>

namespace cg = cooperative_groups;

#define HH 256
#define WW 256
#define BB 64
#define RR 4                 // tap radius: exp(-12.5)=3.7e-6 dropped -> error ~4e-5 << 0.1 thresh
#define OROWS 16             // output rows per unit
#define TROWS (OROWS + 2*RR) // 24 h-blurred rows in LDS
#define TSTR 260             // tmp row stride (dwords): 256 + 4 -> rows rotate 4 banks
#define NUNITS (BB * 16)     // 1024 (b,strip) units

static __device__ __forceinline__ float bin(float v) { return (v > 0.0f) ? 1.0f : 0.0f; }

// ---------------------------------------------------------------------------
// Phase 1 for one (b,strip) unit: copy ch0 strip; for each map m: h-pass
// (global->regs->LDS tmp), v-pass -> write UNNORMALIZED map rows to out ch(m+1),
// strip max -> maxws[b*48 + m*16 + strip] (agent-scope store).
// map 0: x[:,2], s=1.0 -> ch1 ; map 1: x[:,1] -> ch2 ; map 2: x[:,3], s=0.5 -> ch3
// ---------------------------------------------------------------------------
static __device__ __forceinline__ void unit_phase1(
        int unit, int tid,
        const float* __restrict__ x, float* __restrict__ out,
        float* __restrict__ maxws, float* __restrict__ tmp,
        float* __restrict__ wred) {
    const int b = unit >> 4;
    const int strip = unit & 15;
    const int ti0 = strip * OROWS;

    float w1[RR + 1], wh[RR + 1];
#pragma unroll
    for (int d = 0; d <= RR; ++d) {
        w1[d] = __expf(-(float)(d * d) * 0.5f);   // sigma = 1.0
        wh[d] = __expf(-(float)(d * d) * 2.0f);   // sigma = 0.5
    }

    // ---- ch0 strip copy (independent; overlaps with mask loads) ----
    {
        const float4* x0 = (const float4*)(x + (((size_t)b << 2) << 16));
        float4* o0 = (float4*)(out + (((size_t)b * 5) << 16));
        const int base = ti0 << 6;           // float4 index of first row
#pragma unroll
        for (int i = 0; i < 4; ++i) {
            int q = base + (i << 8) + tid;
            o0[q] = x0[q];
        }
    }

    const int c = tid & 63;
    const int gr = tid >> 6;                 // 0..3: one 4-row group per wave

#pragma unroll
    for (int m = 0; m < 3; ++m) {
        const int src_c = (m == 0) ? 2 : ((m == 1) ? 1 : 3);
        const float* wm = (m == 2) ? wh : w1;
        const float* xc = x + ((((size_t)b << 2) + src_c) << 16);

        // ---- h-stage: 24 rows x 32 groups (8 outputs each) = 768 tasks ----
#pragma unroll
        for (int t = 0; t < 3; ++t) {
            int idx = tid + t * 256;
            int r = idx >> 5;                // tmp row 0..23
            int g = idx & 31;                // cols 8g..8g+7
            int gi = ti0 + r - RR;           // image row
            float4 q0 = make_float4(0.f,0.f,0.f,0.f), q1 = q0, q2 = q0, q3 = q0;
            if (gi >= 0 && gi < HH) {
                const float4* row = (const float4*)(xc + ((size_t)gi << 8));
                int i0 = (g > 0) ? (2 * g - 1) : 0;
                int i3 = (g < 31) ? (2 * g + 2) : 63;
                q0 = row[i0];                // halo (L1 hit)
                q1 = row[2 * g];
                q2 = row[2 * g + 1];
                q3 = row[i3];                // halo (L1 hit)
                if (g == 0)  q0 = make_float4(0.f,0.f,0.f,0.f);
                if (g == 31) q3 = make_float4(0.f,0.f,0.f,0.f);
            }
            float a[16] = {bin(q0.x), bin(q0.y), bin(q0.z), bin(q0.w),
                           bin(q1.x), bin(q1.y), bin(q1.z), bin(q1.w),
                           bin(q2.x), bin(q2.y), bin(q2.z), bin(q2.w),
                           bin(q3.x), bin(q3.y), bin(q3.z), bin(q3.w)};
            float o[8];
#pragma unroll
            for (int j = 0; j < 8; ++j) {
                o[j] = wm[4] * (a[j]     + a[j + 8])
                     + wm[3] * (a[j + 1] + a[j + 7])
                     + wm[2] * (a[j + 2] + a[j + 6])
                     + wm[1] * (a[j + 3] + a[j + 5])
                     + wm[0] *  a[j + 4];
            }
            float* trow = &tmp[r * TSTR + 8 * g];
            *(float4*)trow       = make_float4(o[0], o[1], o[2], o[3]);
            *(float4*)(trow + 4) = make_float4(o[4], o[5], o[6], o[7]);
        }
        __syncthreads();

        // ---- v-stage: wave gr -> out rows 4gr..4gr+3, lane c -> cols 4c..4c+3 ----
        float4 acc[4];
#pragma unroll
        for (int rr = 0; rr < 4; ++rr) acc[rr] = make_float4(0.f,0.f,0.f,0.f);
#pragma unroll
        for (int k = 0; k < 12; ++k) {       // all 64 lanes same row, contiguous b128
            float4 v = *(const float4*)&tmp[(4 * gr + k) * TSTR + 4 * c];
#pragma unroll
            for (int rr = 0; rr < 4; ++rr) {
                int d = k - RR - rr;
                if (d >= -RR && d <= RR) {
                    float wk = wm[d < 0 ? -d : d];
                    acc[rr].x += wk * v.x; acc[rr].y += wk * v.y;
                    acc[rr].z += wk * v.z; acc[rr].w += wk * v.w;
                }
            }
        }

        float* oc = out + (((size_t)b * 5 + (m + 1)) << 16);
        float lmax = 0.0f;
#pragma unroll
        for (int rr = 0; rr < 4; ++rr) {
            int row = ti0 + 4 * gr + rr;
            *(float4*)&oc[((size_t)row << 8) + 4 * c] = acc[rr];
            lmax = fmaxf(lmax, fmaxf(fmaxf(acc[rr].x, acc[rr].y), fmaxf(acc[rr].z, acc[rr].w)));
        }

#pragma unroll
        for (int off = 32; off > 0; off >>= 1)
            lmax = fmaxf(lmax, __shfl_down(lmax, off, 64));
        if (c == 0) wred[gr] = lmax;
        __syncthreads();
        if (tid == 0) {
            float mx = fmaxf(fmaxf(wred[0], wred[1]), fmaxf(wred[2], wred[3]));
            __hip_atomic_store(&maxws[b * 48 + m * 16 + strip], mx,
                               __ATOMIC_RELAXED, __HIP_MEMORY_SCOPE_AGENT);
        }
        __syncthreads();                     // tmp + wred reuse across maps/units
    }
}

// ---------------------------------------------------------------------------
// Phase 2 for one unit: reduce the 48 strip maxes of batch b, normalize the
// strip's just-written rows of ch1..3 (L2/L3 hits), write ch4 = t*c.
// ---------------------------------------------------------------------------
static __device__ __forceinline__ void unit_phase2(
        int unit, int tid, float* __restrict__ out,
        const float* __restrict__ maxws, float* __restrict__ smax) {
    const int b = unit >> 4;
    const int strip = unit & 15;
    const int ti0 = strip * OROWS;

    if (tid < 48)
        smax[tid] = __hip_atomic_load(&maxws[b * 48 + tid],
                                      __ATOMIC_RELAXED, __HIP_MEMORY_SCOPE_AGENT);
    __syncthreads();

    float mt = 0.f, mc = 0.f, mh = 0.f;
#pragma unroll
    for (int s = 0; s < 16; ++s) {           // broadcast reads (same addr all lanes)
        mt = fmaxf(mt, smax[s]);
        mc = fmaxf(mc, smax[16 + s]);
        mh = fmaxf(mh, smax[32 + s]);
    }
    if (mt == 0.f) mt = 1.f;
    if (mc == 0.f) mc = 1.f;
    if (mh == 0.f) mh = 1.f;
    const float rt = 1.f / mt, rc = 1.f / mc, rh = 1.f / mh;

    float4* o1 = (float4*)(out + (((size_t)b * 5 + 1) << 16));
    float4* o2 = (float4*)(out + (((size_t)b * 5 + 2) << 16));
    float4* o3 = (float4*)(out + (((size_t)b * 5 + 3) << 16));
    float4* o4 = (float4*)(out + (((size_t)b * 5 + 4) << 16));
    const int base = ti0 << 6;
#pragma unroll
    for (int i = 0; i < 4; ++i) {
        int q = base + (i << 8) + tid;
        float4 t = o1[q], cc = o2[q], h = o3[q];
        t.x *= rt;  t.y *= rt;  t.z *= rt;  t.w *= rt;
        cc.x *= rc; cc.y *= rc; cc.z *= rc; cc.w *= rc;
        h.x *= rh;  h.y *= rh;  h.z *= rh;  h.w *= rh;
        float4 mul = make_float4(t.x * cc.x, t.y * cc.y, t.z * cc.z, t.w * cc.w);
        o1[q] = t;
        o2[q] = cc;
        o3[q] = h;
        o4[q] = mul;
    }
    __syncthreads();                         // smax reuse when a block loops units
}

// ---------------------------------------------------------------------------
// Cooperative fused kernel: grid-stride over units, grid.sync between phases.
// Same block handles a unit in both phases -> phase-2 map reads are L2/L3 hits.
// ---------------------------------------------------------------------------
__global__ __launch_bounds__(256, 4) void fused_kernel(const float* __restrict__ x,
                                                       float* __restrict__ out,
                                                       float* __restrict__ maxws) {
    __shared__ float tmp[TROWS * TSTR];      // 24*260*4 = 24960 B
    __shared__ float wred[4];
    __shared__ float smax[48];

    const int tid = threadIdx.x;
    const int G = gridDim.x;                 // host guarantees G % 8 == 0
    // XCD-chunked swizzle (bijective for G%8==0): contiguous unit runs per XCD.
    const int bid = (blockIdx.x & 7) * (G >> 3) + (blockIdx.x >> 3);

    for (int u = bid; u < NUNITS; u += G)
        unit_phase1(u, tid, x, out, maxws, tmp, wred);

    cg::this_grid().sync();

    for (int u = bid; u < NUNITS; u += G)
        unit_phase2(u, tid, out, maxws, smax);
}

// ---- fallback pair (same device code, plain launches) ----
__global__ __launch_bounds__(256) void phase1_kernel(const float* __restrict__ x,
                                                     float* __restrict__ out,
                                                     float* __restrict__ maxws) {
    __shared__ float tmp[TROWS * TSTR];
    __shared__ float wred[4];
    unit_phase1(blockIdx.x, threadIdx.x, x, out, maxws, tmp, wred);
}

__global__ __launch_bounds__(256) void phase2_kernel(float* __restrict__ out,
                                                     const float* __restrict__ maxws) {
    __shared__ float smax[48];
    unit_phase2(blockIdx.x, threadIdx.x, out, maxws, smax);
}

extern "C" void kernel_launch(void* const* d_in, const int* in_sizes, int n_in,
                              void* d_out, int out_size, void* d_ws, size_t ws_size,
                              hipStream_t stream) {
    const float* x = (const float*)d_in[0];
    float* out = (float*)d_out;
    float* maxws = (float*)d_ws;             // 64*48 floats = 12 KB strip maxes

    // Decide coop grid once (host-side queries only; capture-safe; cached).
    static int G = -2;                       // -2 = undecided, -1 = fallback, >0 = coop grid
    if (G == -2) {
        G = -1;
        hipDeviceProp_t prop{};
        int dev = 0;
        if (hipGetDevice(&dev) == hipSuccess &&
            hipGetDeviceProperties(&prop, dev) == hipSuccess &&
            prop.cooperativeLaunch) {
            int maxb = 0;
            if (hipOccupancyMaxActiveBlocksPerMultiprocessor(
                    &maxb, (const void*)fused_kernel, 256, 0) == hipSuccess && maxb > 0) {
                long lim = (long)maxb * (long)prop.multiProcessorCount;
                long g = (lim < (long)NUNITS) ? lim : (long)NUNITS;
                g = (g / 8) * 8;             // keep XCD swizzle bijective
                if (g >= 8) G = (int)g;
            }
        }
    }

    if (G > 0) {
        void* args[] = { (void*)&x, (void*)&out, (void*)&maxws };
        if (hipLaunchCooperativeKernel((const void*)fused_kernel, dim3(G), dim3(256),
                                       args, 0, stream) == hipSuccess)
            return;
        G = -1;                              // coop rejected at runtime -> permanent fallback
    }

    hipLaunchKernelGGL(phase1_kernel, dim3(NUNITS), dim3(256), 0, stream, x, out, maxws);
    hipLaunchKernelGGL(phase2_kernel, dim3(NUNITS), dim3(256), 0, stream, out, maxws);
}

// Round 3
// 207.681 us; speedup vs baseline: 1.1162x; 1.1162x over previous
//
#include <hip/hip_runtime.h>
#include <cmath>

#define HH 256
#define WW 256
#define BB 64
#define RR 4                 // tap radius: exp(-12.5)=3.7e-6 dropped -> error ~4e-5 << 0.1 thresh
#define OROWS 16             // output rows per block
#define TROWS (OROWS + 2*RR) // 24 h-blurred rows in LDS
#define TSTR 260             // tmp row stride (dwords): 256 + 4 -> rows rotate 4 banks
#define NUNITS (BB * 16)     // 1024 blocks; capacity 5/CU*256 = 1280 -> all resident

static __device__ __forceinline__ float bin(float v) { return (v > 0.0f) ? 1.0f : 0.0f; }
// bf16 truncation pack: rel err <= 2^-8 = 0.4% << 0.101 absmax threshold
static __device__ __forceinline__ unsigned pk2(float a, float b) {
    return (__float_as_uint(a) >> 16) | (__float_as_uint(b) & 0xffff0000u);
}
static __device__ __forceinline__ float up_lo(unsigned u) { return __uint_as_float(u << 16); }
static __device__ __forceinline__ float up_hi(unsigned u) { return __uint_as_float(u & 0xffff0000u); }

// ---------------------------------------------------------------------------
// Single fused kernel, one block per (b, 16-row strip), ALL blocks resident:
//   1. copy ch0 strip
//   2. per map m: h-pass (global->regs->LDS tmp) + v-pass -> acc, keep strip
//      in regs as bf16 (24 VGPRs total), strip-max -> atomicMax(ws[b*3+m])
//   3. per-batch spin: atomicAdd(cnt[b]); wait cnt[b]==16 (16 partner blocks
//      co-resident on the same XCD -> skew ~us). No grid.sync, no L2 flush of
//      bulk data: only 3 scalars/batch cross blocks.
//   4. normalize from regs, write ch1..3 + ch4 = t*c. Maps never round-trip HBM.
// map 0: x[:,2] s=1.0 -> ch1 ; map 1: x[:,1] -> ch2 ; map 2: x[:,3] s=0.5 -> ch3
// ---------------------------------------------------------------------------
__global__ __launch_bounds__(256, 5) void fused_kernel(const float* __restrict__ x,
                                                       float* __restrict__ out,
                                                       int* __restrict__ ws) {
    __shared__ float tmp[TROWS * TSTR];   // 24*260*4 = 24960 B -> 5+ blocks/CU

    int* bmax = ws;                       // [b*3+m] float-as-int maxes (>=0 so int cmp ok)
    int* cnt  = ws + 192;                 // [b] arrival counters (memset to 0 per launch)

    // XCD-chunked swizzle: hw maps bid%8 -> XCD; give each XCD contiguous units
    // so each batch's 16 blocks land on ONE XCD (halo L2 reuse + fast spin).
    const int bid = blockIdx.x;
    const int unit = (bid & 7) * (NUNITS >> 3) + (bid >> 3);
    const int b = unit >> 4;
    const int strip = unit & 15;
    const int ti0 = strip * OROWS;
    const int tid = threadIdx.x;
    const int c = tid & 63;
    const int gr = tid >> 6;              // 0..3: one 4-row group per wave

    // ---- ch0 strip copy (independent; overlaps mask loads) ----
    {
        const float4* x0 = (const float4*)(x + (((size_t)b << 2) << 16));
        float4* o0 = (float4*)(out + (((size_t)b * 5) << 16));
        const int base = ti0 << 6;
#pragma unroll
        for (int i = 0; i < 4; ++i) {
            int q = base + (i << 8) + tid;
            o0[q] = x0[q];
        }
    }

    unsigned pkm[3][8];                   // [map][2*rr+{lo,hi}] bf16-packed strip values

#pragma unroll
    for (int m = 0; m < 3; ++m) {
        const int src_c = (m == 0) ? 2 : ((m == 1) ? 1 : 3);
        const float inv2s2 = (m == 2) ? 2.0f : 0.5f;
        const float* xc = x + ((((size_t)b << 2) + src_c) << 16);

        float wm[RR + 1];
#pragma unroll
        for (int d = 0; d <= RR; ++d) wm[d] = __expf(-(float)(d * d) * inv2s2);

        // ---- h-stage: 24 rows x 32 groups (8 outputs each) = 768 tasks ----
#pragma unroll
        for (int t = 0; t < 3; ++t) {
            int idx = tid + t * 256;
            int r = idx >> 5;             // tmp row 0..23
            int g = idx & 31;             // cols 8g..8g+7
            int gi = ti0 + r - RR;        // image row
            float4 q0 = make_float4(0.f,0.f,0.f,0.f), q1 = q0, q2 = q0, q3 = q0;
            if (gi >= 0 && gi < HH) {
                const float4* row = (const float4*)(xc + ((size_t)gi << 8));
                int i0 = (g > 0) ? (2 * g - 1) : 0;
                int i3 = (g < 31) ? (2 * g + 2) : 63;
                q0 = row[i0];             // halo (L1/L2 hit)
                q1 = row[2 * g];
                q2 = row[2 * g + 1];
                q3 = row[i3];             // halo (L1/L2 hit)
                if (g == 0)  q0 = make_float4(0.f,0.f,0.f,0.f);
                if (g == 31) q3 = make_float4(0.f,0.f,0.f,0.f);
            }
            float a[16] = {bin(q0.x), bin(q0.y), bin(q0.z), bin(q0.w),
                           bin(q1.x), bin(q1.y), bin(q1.z), bin(q1.w),
                           bin(q2.x), bin(q2.y), bin(q2.z), bin(q2.w),
                           bin(q3.x), bin(q3.y), bin(q3.z), bin(q3.w)};
            float o[8];
#pragma unroll
            for (int j = 0; j < 8; ++j) {
                o[j] = wm[4] * (a[j]     + a[j + 8])
                     + wm[3] * (a[j + 1] + a[j + 7])
                     + wm[2] * (a[j + 2] + a[j + 6])
                     + wm[1] * (a[j + 3] + a[j + 5])
                     + wm[0] *  a[j + 4];
            }
            float* trow = &tmp[r * TSTR + 8 * g];
            *(float4*)trow       = make_float4(o[0], o[1], o[2], o[3]);
            *(float4*)(trow + 4) = make_float4(o[4], o[5], o[6], o[7]);
        }
        __syncthreads();

        // ---- v-stage: wave gr -> rows 4gr..4gr+3, lane c -> cols 4c..4c+3 ----
        float4 acc[4];
#pragma unroll
        for (int rr = 0; rr < 4; ++rr) acc[rr] = make_float4(0.f,0.f,0.f,0.f);
#pragma unroll
        for (int k = 0; k < 12; ++k) {    // all 64 lanes same row, contiguous b128
            float4 v = *(const float4*)&tmp[(4 * gr + k) * TSTR + 4 * c];
#pragma unroll
            for (int rr = 0; rr < 4; ++rr) {
                int d = k - RR - rr;
                if (d >= -RR && d <= RR) {
                    float wk = wm[d < 0 ? -d : d];
                    acc[rr].x += wk * v.x; acc[rr].y += wk * v.y;
                    acc[rr].z += wk * v.z; acc[rr].w += wk * v.w;
                }
            }
        }

        float lmax = 0.0f;
#pragma unroll
        for (int rr = 0; rr < 4; ++rr) {
            pkm[m][2 * rr]     = pk2(acc[rr].x, acc[rr].y);
            pkm[m][2 * rr + 1] = pk2(acc[rr].z, acc[rr].w);
            lmax = fmaxf(lmax, fmaxf(fmaxf(acc[rr].x, acc[rr].y), fmaxf(acc[rr].z, acc[rr].w)));
        }
#pragma unroll
        for (int off = 32; off > 0; off >>= 1)
            lmax = fmaxf(lmax, __shfl_down(lmax, off, 64));
        if (c == 0) atomicMax(&bmax[b * 3 + m], __float_as_int(lmax));  // device-scope

        __syncthreads();                  // tmp reuse next map; orders atomicMax pre-signal
    }

    // ---- per-batch barrier: 16 co-resident blocks, 3 scalars cross ----
    if (tid == 0) {
        __hip_atomic_fetch_add(&cnt[b], 1, __ATOMIC_ACQ_REL, __HIP_MEMORY_SCOPE_AGENT);
        while (__hip_atomic_load(&cnt[b], __ATOMIC_ACQUIRE, __HIP_MEMORY_SCOPE_AGENT) < 16)
            __builtin_amdgcn_s_sleep(2);
    }
    __syncthreads();

    float mt = __int_as_float(__hip_atomic_load(&bmax[b * 3 + 0], __ATOMIC_RELAXED,
                                                __HIP_MEMORY_SCOPE_AGENT));
    float mc = __int_as_float(__hip_atomic_load(&bmax[b * 3 + 1], __ATOMIC_RELAXED,
                                                __HIP_MEMORY_SCOPE_AGENT));
    float mh = __int_as_float(__hip_atomic_load(&bmax[b * 3 + 2], __ATOMIC_RELAXED,
                                                __HIP_MEMORY_SCOPE_AGENT));
    if (mt == 0.f) mt = 1.f;
    if (mc == 0.f) mc = 1.f;
    if (mh == 0.f) mh = 1.f;
    const float rt = 1.f / mt, rc = 1.f / mc, rh = 1.f / mh;

    // ---- normalize from registers, single write of ch1..4 ----
    float* o1 = out + (((size_t)b * 5 + 1) << 16);
    float* o2 = out + (((size_t)b * 5 + 2) << 16);
    float* o3 = out + (((size_t)b * 5 + 3) << 16);
    float* o4 = out + (((size_t)b * 5 + 4) << 16);
#pragma unroll
    for (int rr = 0; rr < 4; ++rr) {
        const int row = ti0 + 4 * gr + rr;
        const size_t off = ((size_t)row << 8) + 4 * c;
        unsigned t01 = pkm[0][2 * rr], t23 = pkm[0][2 * rr + 1];
        unsigned c01 = pkm[1][2 * rr], c23 = pkm[1][2 * rr + 1];
        unsigned h01 = pkm[2][2 * rr], h23 = pkm[2][2 * rr + 1];
        float4 t  = make_float4(up_lo(t01) * rt, up_hi(t01) * rt,
                                up_lo(t23) * rt, up_hi(t23) * rt);
        float4 cc = make_float4(up_lo(c01) * rc, up_hi(c01) * rc,
                                up_lo(c23) * rc, up_hi(c23) * rc);
        float4 h  = make_float4(up_lo(h01) * rh, up_hi(h01) * rh,
                                up_lo(h23) * rh, up_hi(h23) * rh);
        float4 mul = make_float4(t.x * cc.x, t.y * cc.y, t.z * cc.z, t.w * cc.w);
        *(float4*)&o1[off] = t;
        *(float4*)&o2[off] = cc;
        *(float4*)&o3[off] = h;
        *(float4*)&o4[off] = mul;
    }
}

extern "C" void kernel_launch(void* const* d_in, const int* in_sizes, int n_in,
                              void* d_out, int out_size, void* d_ws, size_t ws_size,
                              hipStream_t stream) {
    const float* x = (const float*)d_in[0];
    float* out = (float*)d_out;
    int* ws = (int*)d_ws;   // 192 int maxes + 64 int counters = 1024 B

    // Zero maxes+counters every launch (capture-legal memset node).
    hipMemsetAsync(d_ws, 0, 1024, stream);
    hipLaunchKernelGGL(fused_kernel, dim3(NUNITS), dim3(256), 0, stream, x, out, ws);
}